// Round 7
// baseline (2476.120 us; speedup 1.0000x reference)
//
#include <hip/hip_runtime.h>

typedef _Float16 h8 __attribute__((ext_vector_type(8)));
typedef float v4f __attribute__((ext_vector_type(4)));
typedef unsigned long long u64;

#define B_  256
#define T_  512
#define I_  64
#define H_  512

// workspace layout (bytes)
#define OFF_W16   0                                   // [2048][512] f16
#define OFF_WIH   (OFF_W16 + 2048*512*2)              // [2048][64]  f16
#define OFF_BIAS  (OFF_WIH + 2048*64*2)               // [2048]      f32 (b_ih+b_hh)
#define OFF_X16   (OFF_BIAS + 2048*4)                 // [512][256][64] f16 (t-major)
#define OFF_H0    (OFF_X16 + 512*256*64*2)            // [256][512] f16
#define OFF_H1    (OFF_H0 + 256*512*2)                // [256][512] f16
#define OFF_CTR   (OFF_H1 + 256*512*2)                // 16 counters, 64B apart

// LDS chunk stride 1040 = 1024+16 (r6-verified: writes 4 dwords/bank, reads 8/bank)
#define CS_ 1040

__device__ __forceinline__ float sigf(float x) {
    float e = __builtin_amdgcn_exp2f(-1.442695041f * x);
    return __builtin_amdgcn_rcpf(1.f + e);
}
__device__ __forceinline__ float tanhf_(float x) {
    float e = __builtin_amdgcn_exp2f(2.885390082f * x);  // exp(2x)
    return 1.f - 2.f * __builtin_amdgcn_rcpf(e + 1.f);
}

union Pack4 { _Float16 f[4]; u64 u; };

// all-thread poll of ONE uniform counter word (1 coalesced req/wave/check;
// steady-state exits first check -> negligible traffic, unlike r4's flood)
__device__ __forceinline__ void poll_ctr(unsigned* p, unsigned tgt) {
    int guard = 0;
    while (__hip_atomic_load(p, __ATOMIC_RELAXED, __HIP_MEMORY_SCOPE_AGENT) < tgt) {
        __builtin_amdgcn_s_sleep(1);
        if (++guard > (1 << 17)) break;   // anti-hang: fail loud, not silent
    }
}

__global__ void prep_w(const float* __restrict__ Wih, const float* __restrict__ Whh,
                       const float* __restrict__ bih, const float* __restrict__ bhh,
                       _Float16* __restrict__ W16, _Float16* __restrict__ Wih16,
                       float* __restrict__ bias, _Float16* __restrict__ h0,
                       unsigned* __restrict__ ctr) {
    int idx = blockIdx.x * 256 + threadIdx.x;          // grid covers 2048*512
    W16[idx] = (_Float16)Whh[idx];
    if (idx < 2048 * 64)  Wih16[idx] = (_Float16)Wih[idx];
    if (idx < 2048)       bias[idx] = bih[idx] + bhh[idx];
    // h0 zeros must be visible at the IF$ coherence point (lstm_k reads them
    // with device-scope loads that bypass L2) -> device-scope atomic stores.
    if (idx < 32768)
        __hip_atomic_store((u64*)h0 + idx, 0ull,
                           __ATOMIC_RELAXED, __HIP_MEMORY_SCOPE_AGENT);
    if (idx < 256)
        __hip_atomic_store(ctr + idx, 0u, __ATOMIC_RELAXED, __HIP_MEMORY_SCOPE_AGENT);
}

__global__ void prep_x(const float* __restrict__ x, _Float16* __restrict__ x16) {
    int idx = blockIdx.x * 256 + threadIdx.x;          // grid covers 512*256*64
    int t = idx >> 14;                                  // / (256*64)
    int rem = idx & 16383;
    int b = rem >> 6;
    int i = rem & 63;
    x16[idx] = (_Float16)x[((size_t)b * T_ + t) * I_ + i];
}

// 64 wgs: 8 bg-PAIRS x 8 col-groups. wg = TWO batch-groups (p and p+8, 16 rows
// each) x 64 h-cols, sharing the SAME weight fragments (same cg cols). The two
// bg slices form a 2-stage software pipeline: while bgA's h' stores drain and
// its flags/loads fly through IF$, the wave computes bgB's full phase (and
// vice versa). Each poll targets flags published ~1 phase earlier; each h-load
// issues ~1 phase before its staging -> the 4 IF$ round-trips leave the
// critical path. Publish = baseline counter RMW (tid0); poll = all-thread on
// one uniform word. 4 barriers/step (same as baseline), now stall-free.
__launch_bounds__(256, 1)
__global__ void lstm_k(const _Float16* __restrict__ W16, const _Float16* __restrict__ Wih16,
                       const float* __restrict__ bias, const _Float16* __restrict__ x16,
                       _Float16* __restrict__ h0, _Float16* __restrict__ h1,
                       unsigned* __restrict__ ctr) {
    __shared__ __align__(16) char Ab[16 * CS_];   // 16640 B, shared A/B staging

    const int tid  = threadIdx.x;
    const int lane = tid & 63;
    const int wv   = tid >> 6;        // wave = h-col sub-block (0..3)
    const int p    = blockIdx.x & 7;  // bg pair id (XCD-affine: blk%8 == p)
    const int cg   = blockIdx.x >> 3; // column group 0..7
    const int B0A  = p * 16;          // bgA rows
    const int B0B  = B0A + 128;       // bgB rows (p+8)
    const int J0   = cg * 64;         // h-column base
    const int r    = lane & 15;
    const int q    = lane >> 4;

    // --- hoist weights ONCE for both slices: 4 gates x (16 h + 2 x) chunks ---
    h8 bfrag[4][16];
    h8 xbfrag[4][2];
    float biasv[4];
#pragma unroll
    for (int g = 0; g < 4; ++g) {
        const int wrow = g * H_ + J0 + wv * 16 + r;     // gate-col index
#pragma unroll
        for (int kk = 0; kk < 16; ++kk)
            bfrag[g][kk] = *(const h8*)(W16 + (size_t)wrow * H_ + kk * 32 + q * 8);
#pragma unroll
        for (int c = 0; c < 2; ++c)
            xbfrag[g][c] = *(const h8*)(Wih16 + (size_t)wrow * I_ + c * 32 + q * 8);
        biasv[g] = bias[wrow];
    }

    // staging constants (r6-verified): unit u = tid + 256*it ->
    // row = (tid>>7)+2*it, kk = (tid>>3)&15, byte = kk*CS_ + row*64 + (tid&7)*8
    const int wbase = ((tid >> 3) & 15) * CS_ + (tid & 7) * 8;
    const int rw0   = tid >> 7;
    const int rb0   = r * 64 + q * 16;   // phase-B read base

    // cell state: lane owns rows B0?+4q+reg, h-col J0+16wv+r
    float ccA[4] = {0.f, 0.f, 0.f, 0.f};
    float ccB[4] = {0.f, 0.f, 0.f, 0.f};

    unsigned* const ctrA = ctr + (p)     * 16;  // 64B-separated per-bg counters
    unsigned* const ctrB = ctr + (p + 8) * 16;

    // prefetch h_0 (zeros) for bgA, and x_0 fragments for both slices
    u64 hvA[8];
    {
        const u64* hp64 = (const u64*)(h0 + (size_t)B0A * H_);
#pragma unroll
        for (int it = 0; it < 8; ++it)
            hvA[it] = __hip_atomic_load(hp64 + tid + 256 * it,
                                        __ATOMIC_RELAXED, __HIP_MEMORY_SCOPE_AGENT);
    }
    h8 xaA0, xaA1, xaB0, xaB1;
    {
        const _Float16* xrA = x16 + (size_t)(B0A + r) * I_ + q * 8;
        const _Float16* xrB = x16 + (size_t)(B0B + r) * I_ + q * 8;
        xaA0 = *(const h8*)(xrA);  xaA1 = *(const h8*)(xrA + 32);
        xaB0 = *(const h8*)(xrB);  xaB1 = *(const h8*)(xrB + 32);
    }

    for (int s = 0; s < T_; ++s) {
        const _Float16* hp = (s & 1) ? h1 : h0;
        _Float16*       hn = (s & 1) ? h0 : h1;

        // ================= phase A (bg p) =================
#pragma unroll
        for (int it = 0; it < 8; ++it) {           // stage hvA -> LDS
            int row = rw0 + 2 * it;
            *(u64*)(Ab + wbase + row * 64) = hvA[it];
        }
        __syncthreads();                                         // b1

        v4f a0 = {0,0,0,0}, a1 = {0,0,0,0}, a2 = {0,0,0,0}, a3 = {0,0,0,0};
        a0 = __builtin_amdgcn_mfma_f32_16x16x32_f16(xaA0, xbfrag[0][0], a0, 0, 0, 0);
        a1 = __builtin_amdgcn_mfma_f32_16x16x32_f16(xaA0, xbfrag[1][0], a1, 0, 0, 0);
        a2 = __builtin_amdgcn_mfma_f32_16x16x32_f16(xaA0, xbfrag[2][0], a2, 0, 0, 0);
        a3 = __builtin_amdgcn_mfma_f32_16x16x32_f16(xaA0, xbfrag[3][0], a3, 0, 0, 0);
        a0 = __builtin_amdgcn_mfma_f32_16x16x32_f16(xaA1, xbfrag[0][1], a0, 0, 0, 0);
        a1 = __builtin_amdgcn_mfma_f32_16x16x32_f16(xaA1, xbfrag[1][1], a1, 0, 0, 0);
        a2 = __builtin_amdgcn_mfma_f32_16x16x32_f16(xaA1, xbfrag[2][1], a2, 0, 0, 0);
        a3 = __builtin_amdgcn_mfma_f32_16x16x32_f16(xaA1, xbfrag[3][1], a3, 0, 0, 0);

        // poll bgB's h_s (published ~1 phase ago) and issue its loads; they
        // complete during the A-MFMA/cell below.
        u64 hvB[8];
        if (s) poll_ctr(ctrB, 8u * (unsigned)s);
        {
            const u64* hp64 = (const u64*)(hp + (size_t)B0B * H_);
#pragma unroll
            for (int it = 0; it < 8; ++it)
                hvB[it] = __hip_atomic_load(hp64 + tid + 256 * it,
                                            __ATOMIC_RELAXED, __HIP_MEMORY_SCOPE_AGENT);
        }

#pragma unroll
        for (int kk = 0; kk < 16; ++kk) {
            const h8 am = *(const h8*)(Ab + kk * CS_ + rb0);
            a0 = __builtin_amdgcn_mfma_f32_16x16x32_f16(am, bfrag[0][kk], a0, 0, 0, 0);
            a1 = __builtin_amdgcn_mfma_f32_16x16x32_f16(am, bfrag[1][kk], a1, 0, 0, 0);
            a2 = __builtin_amdgcn_mfma_f32_16x16x32_f16(am, bfrag[2][kk], a2, 0, 0, 0);
            a3 = __builtin_amdgcn_mfma_f32_16x16x32_f16(am, bfrag[3][kk], a3, 0, 0, 0);
        }
        {   // cell A + h' stores (C/D: col=lane&15=h-col r, row=q*4+reg=batch)
            unsigned short* hw = (unsigned short*)hn
                               + (size_t)(B0A + q * 4) * H_ + J0 + wv * 16 + r;
#pragma unroll
            for (int reg = 0; reg < 4; ++reg) {
                float iv = sigf  (a0[reg] + biasv[0]);
                float fv = sigf  (a1[reg] + biasv[1]);
                float gv = tanhf_(a2[reg] + biasv[2]);
                float ov = sigf  (a3[reg] + biasv[3]);
                ccA[reg] = fv * ccA[reg] + iv * gv;
                union { _Float16 f; unsigned short u; } cv;
                cv.f = (_Float16)(ov * tanhf_(ccA[reg]));
                __hip_atomic_store(hw + (size_t)reg * H_, cv.u,
                                   __ATOMIC_RELAXED, __HIP_MEMORY_SCOPE_AGENT);
            }
        }
        asm volatile("s_waitcnt vmcnt(0)" ::: "memory");  // h'A ack'd (hvB too)
        if (tid == 0)
            __hip_atomic_fetch_add(ctrA, 1u, __ATOMIC_RELAXED, __HIP_MEMORY_SCOPE_AGENT);
        __syncthreads();                                         // b2 (Ab WAR)

        // ================= phase B (bg p+8) =================
#pragma unroll
        for (int it = 0; it < 8; ++it) {           // stage hvB -> LDS
            int row = rw0 + 2 * it;
            *(u64*)(Ab + wbase + row * 64) = hvB[it];
        }
        __syncthreads();                                         // b3

        v4f b0 = {0,0,0,0}, b1v = {0,0,0,0}, b2v = {0,0,0,0}, b3v = {0,0,0,0};
        b0  = __builtin_amdgcn_mfma_f32_16x16x32_f16(xaB0, xbfrag[0][0], b0, 0, 0, 0);
        b1v = __builtin_amdgcn_mfma_f32_16x16x32_f16(xaB0, xbfrag[1][0], b1v, 0, 0, 0);
        b2v = __builtin_amdgcn_mfma_f32_16x16x32_f16(xaB0, xbfrag[2][0], b2v, 0, 0, 0);
        b3v = __builtin_amdgcn_mfma_f32_16x16x32_f16(xaB0, xbfrag[3][0], b3v, 0, 0, 0);
        b0  = __builtin_amdgcn_mfma_f32_16x16x32_f16(xaB1, xbfrag[0][1], b0, 0, 0, 0);
        b1v = __builtin_amdgcn_mfma_f32_16x16x32_f16(xaB1, xbfrag[1][1], b1v, 0, 0, 0);
        b2v = __builtin_amdgcn_mfma_f32_16x16x32_f16(xaB1, xbfrag[2][1], b2v, 0, 0, 0);
        b3v = __builtin_amdgcn_mfma_f32_16x16x32_f16(xaB1, xbfrag[3][1], b3v, 0, 0, 0);

        // poll bgA's h_{s+1} (we published it ~1 barrier ago; peers likewise),
        // issue bgA loads for next iteration + prefetch next x for both slices.
        if (s + 1 < T_) {
            poll_ctr(ctrA, 8u * (unsigned)(s + 1));
            const u64* hp64 = (const u64*)(hn + (size_t)B0A * H_);
#pragma unroll
            for (int it = 0; it < 8; ++it)
                hvA[it] = __hip_atomic_load(hp64 + tid + 256 * it,
                                            __ATOMIC_RELAXED, __HIP_MEMORY_SCOPE_AGENT);
            const _Float16* xrA = x16 + ((size_t)(s + 1) * B_ + B0A + r) * I_ + q * 8;
            const _Float16* xrB = x16 + ((size_t)(s + 1) * B_ + B0B + r) * I_ + q * 8;
            xaA0 = *(const h8*)(xrA);  xaA1 = *(const h8*)(xrA + 32);
            xaB0 = *(const h8*)(xrB);  xaB1 = *(const h8*)(xrB + 32);
        }

#pragma unroll
        for (int kk = 0; kk < 16; ++kk) {
            const h8 am = *(const h8*)(Ab + kk * CS_ + rb0);
            b0  = __builtin_amdgcn_mfma_f32_16x16x32_f16(am, bfrag[0][kk], b0, 0, 0, 0);
            b1v = __builtin_amdgcn_mfma_f32_16x16x32_f16(am, bfrag[1][kk], b1v, 0, 0, 0);
            b2v = __builtin_amdgcn_mfma_f32_16x16x32_f16(am, bfrag[2][kk], b2v, 0, 0, 0);
            b3v = __builtin_amdgcn_mfma_f32_16x16x32_f16(am, bfrag[3][kk], b3v, 0, 0, 0);
        }
        {   // cell B + h' stores
            unsigned short* hw = (unsigned short*)hn
                               + (size_t)(B0B + q * 4) * H_ + J0 + wv * 16 + r;
#pragma unroll
            for (int reg = 0; reg < 4; ++reg) {
                float iv = sigf  (b0[reg]  + biasv[0]);
                float fv = sigf  (b1v[reg] + biasv[1]);
                float gv = tanhf_(b2v[reg] + biasv[2]);
                float ov = sigf  (b3v[reg] + biasv[3]);
                ccB[reg] = fv * ccB[reg] + iv * gv;
                union { _Float16 f; unsigned short u; } cv;
                cv.f = (_Float16)(ov * tanhf_(ccB[reg]));
                __hip_atomic_store(hw + (size_t)reg * H_, cv.u,
                                   __ATOMIC_RELAXED, __HIP_MEMORY_SCOPE_AGENT);
            }
        }
        asm volatile("s_waitcnt vmcnt(0)" ::: "memory");  // h'B ack'd (hvA' too)
        if (tid == 0)
            __hip_atomic_fetch_add(ctrB, 1u, __ATOMIC_RELAXED, __HIP_MEMORY_SCOPE_AGENT);
        __syncthreads();                                         // b4 (Ab WAR)
    }
}

__global__ void fc_k(const _Float16* __restrict__ hlast, const float* __restrict__ Wfc,
                     const float* __restrict__ bfc, float* __restrict__ out) {
    int b = blockIdx.x;
    int lane = threadIdx.x;   // 64 threads
    // h was written with device-scope stores (bypassing L2) -> read device-scope
    const u64* hp64 = (const u64*)(hlast + (size_t)b * H_);
    Pack4 p0, p1;
    p0.u = __hip_atomic_load(hp64 + lane * 2,     __ATOMIC_RELAXED, __HIP_MEMORY_SCOPE_AGENT);
    p1.u = __hip_atomic_load(hp64 + lane * 2 + 1, __ATOMIC_RELAXED, __HIP_MEMORY_SCOPE_AGENT);
    float sum = 0.f;
#pragma unroll
    for (int j = 0; j < 4; ++j) sum += (float)p0.f[j] * Wfc[lane * 8 + j];
#pragma unroll
    for (int j = 0; j < 4; ++j) sum += (float)p1.f[j] * Wfc[lane * 8 + 4 + j];
    for (int off = 32; off; off >>= 1) sum += __shfl_down(sum, off);
    if (lane == 0) out[b] = sum + bfc[0];
}

extern "C" void kernel_launch(void* const* d_in, const int* in_sizes, int n_in,
                              void* d_out, int out_size, void* d_ws, size_t ws_size,
                              hipStream_t stream) {
    (void)in_sizes; (void)n_in; (void)out_size; (void)ws_size;
    const float* x   = (const float*)d_in[0];
    const float* Wih = (const float*)d_in[1];
    const float* Whh = (const float*)d_in[2];
    const float* bih = (const float*)d_in[3];
    const float* bhh = (const float*)d_in[4];
    const float* Wfc = (const float*)d_in[5];
    const float* bfc = (const float*)d_in[6];
    float* out = (float*)d_out;

    char* ws = (char*)d_ws;
    _Float16* W16   = (_Float16*)(ws + OFF_W16);
    _Float16* Wih16 = (_Float16*)(ws + OFF_WIH);
    float*    biasf = (float*)(ws + OFF_BIAS);
    _Float16* x16   = (_Float16*)(ws + OFF_X16);
    _Float16* h0b   = (_Float16*)(ws + OFF_H0);
    _Float16* h1b   = (_Float16*)(ws + OFF_H1);
    unsigned* ctrb  = (unsigned*)(ws + OFF_CTR);

    hipLaunchKernelGGL(prep_w, dim3((2048 * 512) / 256), dim3(256), 0, stream,
                       Wih, Whh, bih, bhh, W16, Wih16, biasf, h0b, ctrb);
    hipLaunchKernelGGL(prep_x, dim3((512 * 256 * 64) / 256), dim3(256), 0, stream, x, x16);
    hipLaunchKernelGGL(lstm_k, dim3(64), dim3(256), 0, stream,
                       W16, Wih16, biasf, x16, h0b, h1b, ctrb);
    // T=512 even: last write went to buffer 0
    hipLaunchKernelGGL(fc_k, dim3(256), dim3(64), 0, stream, h0b, Wfc, bfc, out);
}

// Round 8
// 1611.808 us; speedup vs baseline: 1.5362x; 1.5362x over previous
//
#include <hip/hip_runtime.h>

typedef _Float16 h8 __attribute__((ext_vector_type(8)));
typedef float v4f __attribute__((ext_vector_type(4)));
typedef unsigned long long u64;

#define B_  256
#define T_  512
#define I_  64
#define H_  512

// workspace layout (bytes)
#define OFF_W16   0                                   // [2048][512] f16
#define OFF_WIH   (OFF_W16 + 2048*512*2)              // [2048][64]  f16
#define OFF_BIAS  (OFF_WIH + 2048*64*2)               // [2048]      f32 (b_ih+b_hh)
#define OFF_X16   (OFF_BIAS + 2048*4)                 // [512][256][64] f16 (t-major)
#define OFF_H0    (OFF_X16 + 512*256*64*2)            // [256][512] f16
#define OFF_H1    (OFF_H0 + 256*512*2)                // [256][512] f16
#define OFF_CTR   (OFF_H1 + 256*512*2)                // [16 bg][8 cg] sentinels, 64B/bg

// LDS chunk stride 1040 = 1024+16 (r6-verified: writes 4 dwords/bank, reads 8/bank)
#define CS_ 1040

__device__ __forceinline__ float sigf(float x) {
    float e = __builtin_amdgcn_exp2f(-1.442695041f * x);
    return __builtin_amdgcn_rcpf(1.f + e);
}
__device__ __forceinline__ float tanhf_(float x) {
    float e = __builtin_amdgcn_exp2f(2.885390082f * x);  // exp(2x)
    return 1.f - 2.f * __builtin_amdgcn_rcpf(e + 1.f);
}

union Pack4 { _Float16 f[4]; u64 u; };

__global__ void prep_w(const float* __restrict__ Wih, const float* __restrict__ Whh,
                       const float* __restrict__ bih, const float* __restrict__ bhh,
                       _Float16* __restrict__ W16, _Float16* __restrict__ Wih16,
                       float* __restrict__ bias, _Float16* __restrict__ h0,
                       unsigned* __restrict__ ctr) {
    int idx = blockIdx.x * 256 + threadIdx.x;          // grid covers 2048*512
    W16[idx] = (_Float16)Whh[idx];
    if (idx < 2048 * 64)  Wih16[idx] = (_Float16)Wih[idx];
    if (idx < 2048)       bias[idx] = bih[idx] + bhh[idx];
    // h0 zeros must be visible at the IF$ coherence point (lstm_k reads them
    // with device-scope loads that bypass L2) -> device-scope atomic stores.
    if (idx < 32768)
        __hip_atomic_store((u64*)h0 + idx, 0ull,
                           __ATOMIC_RELAXED, __HIP_MEMORY_SCOPE_AGENT);
    if (idx < 256)
        __hip_atomic_store(ctr + idx, 0u, __ATOMIC_RELAXED, __HIP_MEMORY_SCOPE_AGENT);
}

__global__ void prep_x(const float* __restrict__ x, _Float16* __restrict__ x16) {
    int idx = blockIdx.x * 256 + threadIdx.x;          // grid covers 512*256*64
    int t = idx >> 14;                                  // / (256*64)
    int rem = idx & 16383;
    int b = rem >> 6;
    int i = rem & 63;
    x16[idx] = (_Float16)x[((size_t)b * T_ + t) * I_ + i];
}

// 128 wgs: 16 batch-groups x 8 col-groups. wg = 16 batch rows x 64 h-cols.
// Wave wv owns h-cols J0+16wv..+15 for ALL FOUR gates (bfrag[4][16]) ->
// LSTM cell fully in registers (r6-verified structure, 1439us).
// r8 delta (ONLY the publish protocol): the per-bg rendezvous was 8
// agent-scope fetch_adds to ONE word -> same-line RMWs serialize at the
// coherence point (~300-500cy each = ~2500-4000cy/step hidden chain).
// Now: each producer-wg stores its OWN sentinel word (8 words per bg in one
// 32B region; independent stores pipeline at the MALL, no ownership chain).
// Poll stays tid==0-only (r4 proved wide polls flood the fabric): 8 pipelined
// word loads per probe ~= 1 round-trip.
__launch_bounds__(256, 1)
__global__ void lstm_k(const _Float16* __restrict__ W16, const _Float16* __restrict__ Wih16,
                       const float* __restrict__ bias, const _Float16* __restrict__ x16,
                       _Float16* __restrict__ h0, _Float16* __restrict__ h1,
                       unsigned* __restrict__ ctr) {
    __shared__ __align__(16) char Ab[16 * CS_];   // 16640 B, h-tile staging

    const int tid  = threadIdx.x;
    const int lane = tid & 63;
    const int wv   = tid >> 6;        // wave = h-col sub-block (0..3)
    const int bg   = blockIdx.x & 15; // batch group (16 rows)
    const int cg   = blockIdx.x >> 4; // column group 0..7
    const int B0   = bg * 16;
    const int J0   = cg * 64;         // h-column base
    const int r    = lane & 15;
    const int q    = lane >> 4;

    // --- hoist weights: 4 gates x 16 h-chunks + 2 x-chunks (~290 VGPRs) ---
    h8 bfrag[4][16];
    h8 xbfrag[4][2];
    float biasv[4];
#pragma unroll
    for (int g = 0; g < 4; ++g) {
        const int wrow = g * H_ + J0 + wv * 16 + r;     // gate-col index
#pragma unroll
        for (int kk = 0; kk < 16; ++kk)
            bfrag[g][kk] = *(const h8*)(W16 + (size_t)wrow * H_ + kk * 32 + q * 8);
#pragma unroll
        for (int c = 0; c < 2; ++c)
            xbfrag[g][c] = *(const h8*)(Wih16 + (size_t)wrow * I_ + c * 32 + q * 8);
        biasv[g] = bias[wrow];
    }

    // staging constants: unit u = tid + 256*it -> row = (tid>>7)+2*it,
    // kk = (tid>>3)&15, byte = kk*CS_ + row*64 + (tid&7)*8
    const int wbase = ((tid >> 3) & 15) * CS_ + (tid & 7) * 8;
    const int rw0   = tid >> 7;
    // phase-B read base: chunk kk, row r, bytes q*16..
    const int rb0 = r * 64 + q * 16;

    // cell state: lane owns batch rows B0+4q+reg, h-col J0+16wv+r
    float cc[4] = {0.f, 0.f, 0.f, 0.f};

    unsigned* const mysnt = ctr + bg * 16;  // 8 sentinel words (32B) per bg

    // x A-frags for step 0: lane (r,q) needs x16[t][B0+r][c*32 + q*8 ..+7]
    const _Float16* xrow0 = x16 + (size_t)(B0 + r) * I_ + q * 8;
    h8 xa0 = *(const h8*)(xrow0);
    h8 xa1 = *(const h8*)(xrow0 + 32);

    for (int s = 0; s < T_; ++s) {
        const _Float16* hp = (s & 1) ? h1 : h0;
        _Float16*       hn = (s & 1) ? h0 : h1;

        // ---- phase A: issue h agent-loads (bypass L1/L2) ----
        u64 hv[8];
        {
            const u64* hp64 = (const u64*)(hp + (size_t)B0 * H_);
#pragma unroll
            for (int it = 0; it < 8; ++it)
                hv[it] = __hip_atomic_load(hp64 + tid + 256 * it,
                                           __ATOMIC_RELAXED, __HIP_MEMORY_SCOPE_AGENT);
        }

        // ---- x-part MFMAs overlap the h-load latency (register-only) ----
        v4f a0 = {0,0,0,0}, a1 = {0,0,0,0}, a2 = {0,0,0,0}, a3 = {0,0,0,0};
        a0 = __builtin_amdgcn_mfma_f32_16x16x32_f16(xa0, xbfrag[0][0], a0, 0, 0, 0);
        a1 = __builtin_amdgcn_mfma_f32_16x16x32_f16(xa0, xbfrag[1][0], a1, 0, 0, 0);
        a2 = __builtin_amdgcn_mfma_f32_16x16x32_f16(xa0, xbfrag[2][0], a2, 0, 0, 0);
        a3 = __builtin_amdgcn_mfma_f32_16x16x32_f16(xa0, xbfrag[3][0], a3, 0, 0, 0);
        a0 = __builtin_amdgcn_mfma_f32_16x16x32_f16(xa1, xbfrag[0][1], a0, 0, 0, 0);
        a1 = __builtin_amdgcn_mfma_f32_16x16x32_f16(xa1, xbfrag[1][1], a1, 0, 0, 0);
        a2 = __builtin_amdgcn_mfma_f32_16x16x32_f16(xa1, xbfrag[2][1], a2, 0, 0, 0);
        a3 = __builtin_amdgcn_mfma_f32_16x16x32_f16(xa1, xbfrag[3][1], a3, 0, 0, 0);

        // ---- stage h into LDS (waits loads), barrier ----
#pragma unroll
        for (int it = 0; it < 8; ++it) {
            int row = rw0 + 2 * it;
            *(u64*)(Ab + wbase + row * 64) = hv[it];
        }
        __syncthreads();

        // ---- phase B: h-part MFMA, 16 chunks; one A-frag feeds 4 gates ----
#pragma unroll
        for (int kk = 0; kk < 16; ++kk) {
            const h8 am = *(const h8*)(Ab + kk * CS_ + rb0);
            a0 = __builtin_amdgcn_mfma_f32_16x16x32_f16(am, bfrag[0][kk], a0, 0, 0, 0);
            a1 = __builtin_amdgcn_mfma_f32_16x16x32_f16(am, bfrag[1][kk], a1, 0, 0, 0);
            a2 = __builtin_amdgcn_mfma_f32_16x16x32_f16(am, bfrag[2][kk], a2, 0, 0, 0);
            a3 = __builtin_amdgcn_mfma_f32_16x16x32_f16(am, bfrag[3][kk], a3, 0, 0, 0);
        }

        // ---- phase C: LSTM cell in registers; h' as 4x2B agent stores ----
        // C/D [m89/r2-verified]: col = lane&15 = h-col r; row = q*4+reg = batch
        {
            unsigned short* hw = (unsigned short*)hn
                               + (size_t)(B0 + q * 4) * H_ + J0 + wv * 16 + r;
#pragma unroll
            for (int reg = 0; reg < 4; ++reg) {
                float iv = sigf  (a0[reg] + biasv[0]);
                float fv = sigf  (a1[reg] + biasv[1]);
                float gv = tanhf_(a2[reg] + biasv[2]);
                float ov = sigf  (a3[reg] + biasv[3]);
                cc[reg] = fv * cc[reg] + iv * gv;
                union { _Float16 f; unsigned short u; } cv;
                cv.f = (_Float16)(ov * tanhf_(cc[reg]));
                __hip_atomic_store(hw + (size_t)reg * H_, cv.u,
                                   __ATOMIC_RELAXED, __HIP_MEMORY_SCOPE_AGENT);
            }
        }
        __syncthreads();   // implicit vmcnt(0): all lanes' h stores ack'd at IF$

        // ---- publish: plain sentinel store to OWN word (no RMW chain) ----
        if (tid == 0)
            __hip_atomic_store(mysnt + cg, (unsigned)(s + 1),
                               __ATOMIC_RELAXED, __HIP_MEMORY_SCOPE_AGENT);
        // x A-frag prefetch for s+1 overlaps the poll
        if (s + 1 < T_) {
            const _Float16* xr = x16 + ((size_t)(s + 1) * B_ + B0 + r) * I_ + q * 8;
            xa0 = *(const h8*)(xr);
            xa1 = *(const h8*)(xr + 32);
        }
        // ---- poll: tid==0 reads the bg's 8 sentinels (pipelined loads) ----
        if (tid == 0) {
            const unsigned tgt = (unsigned)(s + 1);
            int guard = 0;
            for (;;) {
                unsigned m0 = 0xffffffffu;
#pragma unroll
                for (int j = 0; j < 8; ++j) {
                    unsigned v = __hip_atomic_load(mysnt + j,
                                                   __ATOMIC_RELAXED, __HIP_MEMORY_SCOPE_AGENT);
                    m0 = v < m0 ? v : m0;
                }
                if (m0 >= tgt) break;
                __builtin_amdgcn_s_sleep(1);
                if (++guard > (1 << 17)) break;   // anti-hang: fail loud, not silent
            }
        }
        __syncthreads();
    }
}

__global__ void fc_k(const _Float16* __restrict__ hlast, const float* __restrict__ Wfc,
                     const float* __restrict__ bfc, float* __restrict__ out) {
    int b = blockIdx.x;
    int lane = threadIdx.x;   // 64 threads
    // h was written with device-scope stores (bypassing L2) -> read device-scope
    const u64* hp64 = (const u64*)(hlast + (size_t)b * H_);
    Pack4 p0, p1;
    p0.u = __hip_atomic_load(hp64 + lane * 2,     __ATOMIC_RELAXED, __HIP_MEMORY_SCOPE_AGENT);
    p1.u = __hip_atomic_load(hp64 + lane * 2 + 1, __ATOMIC_RELAXED, __HIP_MEMORY_SCOPE_AGENT);
    float sum = 0.f;
#pragma unroll
    for (int j = 0; j < 4; ++j) sum += (float)p0.f[j] * Wfc[lane * 8 + j];
#pragma unroll
    for (int j = 0; j < 4; ++j) sum += (float)p1.f[j] * Wfc[lane * 8 + 4 + j];
    for (int off = 32; off; off >>= 1) sum += __shfl_down(sum, off);
    if (lane == 0) out[b] = sum + bfc[0];
}

extern "C" void kernel_launch(void* const* d_in, const int* in_sizes, int n_in,
                              void* d_out, int out_size, void* d_ws, size_t ws_size,
                              hipStream_t stream) {
    (void)in_sizes; (void)n_in; (void)out_size; (void)ws_size;
    const float* x   = (const float*)d_in[0];
    const float* Wih = (const float*)d_in[1];
    const float* Whh = (const float*)d_in[2];
    const float* bih = (const float*)d_in[3];
    const float* bhh = (const float*)d_in[4];
    const float* Wfc = (const float*)d_in[5];
    const float* bfc = (const float*)d_in[6];
    float* out = (float*)d_out;

    char* ws = (char*)d_ws;
    _Float16* W16   = (_Float16*)(ws + OFF_W16);
    _Float16* Wih16 = (_Float16*)(ws + OFF_WIH);
    float*    biasf = (float*)(ws + OFF_BIAS);
    _Float16* x16   = (_Float16*)(ws + OFF_X16);
    _Float16* h0b   = (_Float16*)(ws + OFF_H0);
    _Float16* h1b   = (_Float16*)(ws + OFF_H1);
    unsigned* ctrb  = (unsigned*)(ws + OFF_CTR);

    hipLaunchKernelGGL(prep_w, dim3((2048 * 512) / 256), dim3(256), 0, stream,
                       Wih, Whh, bih, bhh, W16, Wih16, biasf, h0b, ctrb);
    hipLaunchKernelGGL(prep_x, dim3((512 * 256 * 64) / 256), dim3(256), 0, stream, x, x16);
    hipLaunchKernelGGL(lstm_k, dim3(128), dim3(256), 0, stream,
                       W16, Wih16, biasf, x16, h0b, h1b, ctrb);
    // T=512 even: last write went to buffer 0
    hipLaunchKernelGGL(fc_k, dim3(256), dim3(64), 0, stream, h0b, Wfc, bfc, out);
}

// Round 9
// 1371.294 us; speedup vs baseline: 1.8057x; 1.1754x over previous
//
#include <hip/hip_runtime.h>

typedef _Float16 h8 __attribute__((ext_vector_type(8)));
typedef float v4f __attribute__((ext_vector_type(4)));
typedef unsigned long long u64;

#define B_  256
#define T_  512
#define I_  64
#define H_  512

// workspace layout (bytes)
#define OFF_W16   0                                   // [2048][512] f16
#define OFF_WIH   (OFF_W16 + 2048*512*2)              // [2048][64]  f16
#define OFF_BIAS  (OFF_WIH + 2048*64*2)               // [2048]      f32 (b_ih+b_hh)
#define OFF_X16   (OFF_BIAS + 2048*4)                 // [512][256][64] f16 (t-major)
#define OFF_H0    (OFF_X16 + 512*256*64*2)            // [256][512] f16
#define OFF_H1    (OFF_H0 + 256*512*2)                // [256][512] f16
#define OFF_CTR   (OFF_H1 + 256*512*2)                // 16 counters, 64B apart

// LDS chunk stride 1040 = 1024+16 (r6-verified: writes 4 dwords/bank, reads 8/bank)
#define CS_ 1040

__device__ __forceinline__ float sigf(float x) {
    float e = __builtin_amdgcn_exp2f(-1.442695041f * x);
    return __builtin_amdgcn_rcpf(1.f + e);
}
__device__ __forceinline__ float tanhf_(float x) {
    float e = __builtin_amdgcn_exp2f(2.885390082f * x);  // exp(2x)
    return 1.f - 2.f * __builtin_amdgcn_rcpf(e + 1.f);
}

union Pack4 { _Float16 f[4]; u64 u; };

__global__ void prep_w(const float* __restrict__ Wih, const float* __restrict__ Whh,
                       const float* __restrict__ bih, const float* __restrict__ bhh,
                       _Float16* __restrict__ W16, _Float16* __restrict__ Wih16,
                       float* __restrict__ bias, _Float16* __restrict__ h0,
                       unsigned* __restrict__ ctr) {
    int idx = blockIdx.x * 256 + threadIdx.x;          // grid covers 2048*512
    W16[idx] = (_Float16)Whh[idx];
    if (idx < 2048 * 64)  Wih16[idx] = (_Float16)Wih[idx];
    if (idx < 2048)       bias[idx] = bih[idx] + bhh[idx];
    // h0 zeros must be visible at the IF$ coherence point (lstm_k reads them
    // with device-scope loads that bypass L2) -> device-scope atomic stores.
    if (idx < 32768)
        __hip_atomic_store((u64*)h0 + idx, 0ull,
                           __ATOMIC_RELAXED, __HIP_MEMORY_SCOPE_AGENT);
    if (idx < 256)
        __hip_atomic_store(ctr + idx, 0u, __ATOMIC_RELAXED, __HIP_MEMORY_SCOPE_AGENT);
}

__global__ void prep_x(const float* __restrict__ x, _Float16* __restrict__ x16) {
    int idx = blockIdx.x * 256 + threadIdx.x;          // grid covers 512*256*64
    int t = idx >> 14;                                  // / (256*64)
    int rem = idx & 16383;
    int b = rem >> 6;
    int i = rem & 63;
    x16[idx] = (_Float16)x[((size_t)b * T_ + t) * I_ + i];
}

// r6 structure (1380us steady, proven) with two local deltas:
//  (1) OPERAND SWAP: mfma(A=W, B=h). A/B lane mappings are symmetric, so the
//      weight-fragment addresses AND the LDS h-read addresses are byte-
//      identical to r6 -- only the mfma argument order changes. C/D then
//      gives each lane 4 CONSECUTIVE h-cols of one batch row -> the h' write
//      becomes ONE packed 8B agent store (was 4x2B scatter): 4x fewer store
//      transactions on the drain + store-visibility tail. (r3 passed the
//      harness with this exact swapped structure -> correctness proven.)
//  (2) PUBLISH SHORTCUT: use fetch_add's return. If old+1==target, this wg
//      is the LAST publisher -> peers all published -> skip the poll round
//      trip. The slowest producer is usually last, and its detect latency IS
//      the critical path.
// Protocol otherwise EXACTLY r6 (counter RMW + tid0 single-word poll; r4/r7/r8
// proved every other protocol variant regresses).
__launch_bounds__(256, 1)
__global__ void lstm_k(const _Float16* __restrict__ W16, const _Float16* __restrict__ Wih16,
                       const float* __restrict__ bias, const _Float16* __restrict__ x16,
                       _Float16* __restrict__ h0, _Float16* __restrict__ h1,
                       unsigned* __restrict__ ctr) {
    __shared__ __align__(16) char Ab[16 * CS_];   // 16640 B, h-tile staging

    const int tid  = threadIdx.x;
    const int lane = tid & 63;
    const int wv   = tid >> 6;        // wave = h-col sub-block (0..3)
    const int bg   = blockIdx.x & 15; // batch group (16 rows)
    const int cg   = blockIdx.x >> 4; // column group 0..7
    const int B0   = bg * 16;
    const int J0   = cg * 64;         // h-column base
    const int r    = lane & 15;
    const int q    = lane >> 4;

    // --- hoist weights as A-frags: 4 gates x 16 h-chunks + 2 x-chunks ---
    // (addresses identical to r6's bfrag loads; role is now the A operand)
    h8 afrag[4][16];
    h8 xafrag[4][2];
    float biasv[4][4];
#pragma unroll
    for (int g = 0; g < 4; ++g) {
        const int wrow = g * H_ + J0 + wv * 16 + r;     // gate-col index (A row)
#pragma unroll
        for (int kk = 0; kk < 16; ++kk)
            afrag[g][kk] = *(const h8*)(W16 + (size_t)wrow * H_ + kk * 32 + q * 8);
#pragma unroll
        for (int c = 0; c < 2; ++c)
            xafrag[g][c] = *(const h8*)(Wih16 + (size_t)wrow * I_ + c * 32 + q * 8);
        // D rows (M=gate-col) = q*4+reg -> bias per (g, reg)
#pragma unroll
        for (int reg = 0; reg < 4; ++reg)
            biasv[g][reg] = bias[g * H_ + J0 + wv * 16 + q * 4 + reg];
    }

    // staging constants: unit u = tid + 256*it -> row = (tid>>7)+2*it,
    // kk = (tid>>3)&15, byte = kk*CS_ + row*64 + (tid&7)*8
    const int wbase = ((tid >> 3) & 15) * CS_ + (tid & 7) * 8;
    const int rw0   = tid >> 7;
    // B-frag (h) read base: chunk kk, batch row r, bytes q*16.. (same as r6)
    const int rb0 = r * 64 + q * 16;

    // cell state: lane owns batch row B0+r, h-cols J0+wv*16+q*4+{0..3}
    float cc[4] = {0.f, 0.f, 0.f, 0.f};

    unsigned* myctr = ctr + bg * 16;  // 64B-separated per-bg counters

    // x B-frags for step 0: lane (r,q) needs x16[t][B0+r][c*32 + q*8 ..+7]
    const _Float16* xrow0 = x16 + (size_t)(B0 + r) * I_ + q * 8;
    h8 xa0 = *(const h8*)(xrow0);
    h8 xa1 = *(const h8*)(xrow0 + 32);

    for (int s = 0; s < T_; ++s) {
        const _Float16* hp = (s & 1) ? h1 : h0;
        _Float16*       hn = (s & 1) ? h0 : h1;

        // ---- phase A: issue h agent-loads (bypass L1/L2) ----
        u64 hv[8];
        {
            const u64* hp64 = (const u64*)(hp + (size_t)B0 * H_);
#pragma unroll
            for (int it = 0; it < 8; ++it)
                hv[it] = __hip_atomic_load(hp64 + tid + 256 * it,
                                           __ATOMIC_RELAXED, __HIP_MEMORY_SCOPE_AGENT);
        }

        // ---- x-part MFMAs overlap the h-load latency (register-only) ----
        v4f a0 = {0,0,0,0}, a1 = {0,0,0,0}, a2 = {0,0,0,0}, a3 = {0,0,0,0};
        a0 = __builtin_amdgcn_mfma_f32_16x16x32_f16(xafrag[0][0], xa0, a0, 0, 0, 0);
        a1 = __builtin_amdgcn_mfma_f32_16x16x32_f16(xafrag[1][0], xa0, a1, 0, 0, 0);
        a2 = __builtin_amdgcn_mfma_f32_16x16x32_f16(xafrag[2][0], xa0, a2, 0, 0, 0);
        a3 = __builtin_amdgcn_mfma_f32_16x16x32_f16(xafrag[3][0], xa0, a3, 0, 0, 0);
        a0 = __builtin_amdgcn_mfma_f32_16x16x32_f16(xafrag[0][1], xa1, a0, 0, 0, 0);
        a1 = __builtin_amdgcn_mfma_f32_16x16x32_f16(xafrag[1][1], xa1, a1, 0, 0, 0);
        a2 = __builtin_amdgcn_mfma_f32_16x16x32_f16(xafrag[2][1], xa1, a2, 0, 0, 0);
        a3 = __builtin_amdgcn_mfma_f32_16x16x32_f16(xafrag[3][1], xa1, a3, 0, 0, 0);

        // ---- stage h into LDS (waits loads), barrier ----
#pragma unroll
        for (int it = 0; it < 8; ++it) {
            int row = rw0 + 2 * it;
            *(u64*)(Ab + wbase + row * 64) = hv[it];
        }
        __syncthreads();

        // ---- phase B: h-part MFMA, 16 chunks; B-frag (h) feeds 4 gates ----
#pragma unroll
        for (int kk = 0; kk < 16; ++kk) {
            const h8 bm = *(const h8*)(Ab + kk * CS_ + rb0);
            a0 = __builtin_amdgcn_mfma_f32_16x16x32_f16(afrag[0][kk], bm, a0, 0, 0, 0);
            a1 = __builtin_amdgcn_mfma_f32_16x16x32_f16(afrag[1][kk], bm, a1, 0, 0, 0);
            a2 = __builtin_amdgcn_mfma_f32_16x16x32_f16(afrag[2][kk], bm, a2, 0, 0, 0);
            a3 = __builtin_amdgcn_mfma_f32_16x16x32_f16(afrag[3][kk], bm, a3, 0, 0, 0);
        }

        // ---- phase C: cell in registers; ONE packed 8B h' store per lane ----
        // C/D [m89]: col = lane&15 = batch r; row = q*4+reg = h-col offset
        {
            Pack4 pk;
#pragma unroll
            for (int reg = 0; reg < 4; ++reg) {
                float iv = sigf  (a0[reg] + biasv[0][reg]);
                float fv = sigf  (a1[reg] + biasv[1][reg]);
                float gv = tanhf_(a2[reg] + biasv[2][reg]);
                float ov = sigf  (a3[reg] + biasv[3][reg]);
                cc[reg] = fv * cc[reg] + iv * gv;
                pk.f[reg] = (_Float16)(ov * tanhf_(cc[reg]));
            }
            __hip_atomic_store(
                (u64*)(hn + (size_t)(B0 + r) * H_ + J0 + wv * 16 + q * 4),
                pk.u, __ATOMIC_RELAXED, __HIP_MEMORY_SCOPE_AGENT);
        }
        __syncthreads();   // implicit vmcnt(0): all lanes' h stores ack'd at IF$

        // ---- per-group barrier: counter RMW; last publisher skips the poll ----
        unsigned old = 0;
        const unsigned target = 8u * (unsigned)(s + 1);
        if (tid == 0)
            old = __hip_atomic_fetch_add(myctr, 1u,
                                         __ATOMIC_RELAXED, __HIP_MEMORY_SCOPE_AGENT);
        // x B-frag prefetch for s+1 overlaps the RMW/poll
        if (s + 1 < T_) {
            const _Float16* xr = x16 + ((size_t)(s + 1) * B_ + B0 + r) * I_ + q * 8;
            xa0 = *(const h8*)(xr);
            xa1 = *(const h8*)(xr + 32);
        }
        if (tid == 0 && old + 1 < target) {
            int guard = 0;
            while (__hip_atomic_load(myctr, __ATOMIC_RELAXED, __HIP_MEMORY_SCOPE_AGENT) < target) {
                __builtin_amdgcn_s_sleep(1);
                if (++guard > (1 << 17)) break;   // anti-hang: fail loud, not silent
            }
        }
        __syncthreads();
    }
}

__global__ void fc_k(const _Float16* __restrict__ hlast, const float* __restrict__ Wfc,
                     const float* __restrict__ bfc, float* __restrict__ out) {
    int b = blockIdx.x;
    int lane = threadIdx.x;   // 64 threads
    // h was written with device-scope stores (bypassing L2) -> read device-scope
    const u64* hp64 = (const u64*)(hlast + (size_t)b * H_);
    Pack4 p0, p1;
    p0.u = __hip_atomic_load(hp64 + lane * 2,     __ATOMIC_RELAXED, __HIP_MEMORY_SCOPE_AGENT);
    p1.u = __hip_atomic_load(hp64 + lane * 2 + 1, __ATOMIC_RELAXED, __HIP_MEMORY_SCOPE_AGENT);
    float sum = 0.f;
#pragma unroll
    for (int j = 0; j < 4; ++j) sum += (float)p0.f[j] * Wfc[lane * 8 + j];
#pragma unroll
    for (int j = 0; j < 4; ++j) sum += (float)p1.f[j] * Wfc[lane * 8 + 4 + j];
    for (int off = 32; off; off >>= 1) sum += __shfl_down(sum, off);
    if (lane == 0) out[b] = sum + bfc[0];
}

extern "C" void kernel_launch(void* const* d_in, const int* in_sizes, int n_in,
                              void* d_out, int out_size, void* d_ws, size_t ws_size,
                              hipStream_t stream) {
    (void)in_sizes; (void)n_in; (void)out_size; (void)ws_size;
    const float* x   = (const float*)d_in[0];
    const float* Wih = (const float*)d_in[1];
    const float* Whh = (const float*)d_in[2];
    const float* bih = (const float*)d_in[3];
    const float* bhh = (const float*)d_in[4];
    const float* Wfc = (const float*)d_in[5];
    const float* bfc = (const float*)d_in[6];
    float* out = (float*)d_out;

    char* ws = (char*)d_ws;
    _Float16* W16   = (_Float16*)(ws + OFF_W16);
    _Float16* Wih16 = (_Float16*)(ws + OFF_WIH);
    float*    biasf = (float*)(ws + OFF_BIAS);
    _Float16* x16   = (_Float16*)(ws + OFF_X16);
    _Float16* h0b   = (_Float16*)(ws + OFF_H0);
    _Float16* h1b   = (_Float16*)(ws + OFF_H1);
    unsigned* ctrb  = (unsigned*)(ws + OFF_CTR);

    hipLaunchKernelGGL(prep_w, dim3((2048 * 512) / 256), dim3(256), 0, stream,
                       Wih, Whh, bih, bhh, W16, Wih16, biasf, h0b, ctrb);
    hipLaunchKernelGGL(prep_x, dim3((512 * 256 * 64) / 256), dim3(256), 0, stream, x, x16);
    hipLaunchKernelGGL(lstm_k, dim3(128), dim3(256), 0, stream,
                       W16, Wih16, biasf, x16, h0b, h1b, ctrb);
    // T=512 even: last write went to buffer 0
    hipLaunchKernelGGL(fc_k, dim3(256), dim3(64), 0, stream, h0b, Wfc, bfc, out);
}